// Round 2
// baseline (146.444 us; speedup 1.0000x reference)
//
#include <hip/hip_runtime.h>

// out[b,c,m] = max_n x[b,c,n] * Bt[m,n],  Bt binary {0,1}, ~3 ones per row of 2048.
// Exact sparse formulation:
//   row has a zero (always in practice) -> out = max(0, max over ones of x)
//   row all ones / list overflow        -> dense fallback kernel (never runs here)
// Positive floats compare correctly as uint bit patterns -> atomicMax on bits,
// with out pre-zeroed (0 bits == 0.0f == the clamp). Non-positive x skipped.
//
// Pipeline: (1) compact Bt -> packed (m,n) list  [pure stream, near-HBM-BW]
//           (2) scatter: nnz*32 dense updates    [tiny]
//           (3) fallback guard                   [early-out]

#define HG_N_IN   2048
#define HG_N_OUT  4096
#define HG_BC     32      // BATCH * FEAT = 2*16

// ws layout (bytes):
//   [0]      int   nnz counter
//   [4]      int   overflow flag
//   [16]     int   counts[4096]        (per-row nonzero count, all-ones detect)
//   [16400]  uint  list[capacity]      (packed entries: (m<<11)|n, 23 bits)
#define WS_COUNTS_OFF  16
#define WS_LIST_OFF    16400

__global__ void hg_compact(const float4* __restrict__ Bt4,
                           unsigned int* __restrict__ outBits,
                           int* __restrict__ counter,
                           int* __restrict__ overflow,
                           int* __restrict__ counts,
                           unsigned int* __restrict__ list,
                           int capacity, int totalVec) {
    const int tid = blockIdx.x * blockDim.x + threadIdx.x;
    const int stride = gridDim.x * blockDim.x;
    // fold output zeroing into the streaming kernel (scatter runs next dispatch)
    if (tid < HG_BC * HG_N_OUT) outBits[tid] = 0u;
    for (int i = tid; i < totalVec; i += stride) {
        float4 v = Bt4[i];
        int f0 = (v.x != 0.0f), f1 = (v.y != 0.0f);
        int f2 = (v.z != 0.0f), f3 = (v.w != 0.0f);
        int cnt = f0 + f1 + f2 + f3;
        if (cnt == 0) continue;                    // 99.4% of threads
        int e  = i << 2;
        int m  = e >> 11;                          // row (float4 never crosses rows)
        int n0 = e & (HG_N_IN - 1);
        atomicAdd(&counts[m], cnt);
        int base = atomicAdd(counter, cnt);
        int k = 0;
        #pragma unroll
        for (int j = 0; j < 4; ++j) {
            int flag = (j == 0) ? f0 : (j == 1) ? f1 : (j == 2) ? f2 : f3;
            if (flag) {
                int pos = base + (k++);
                unsigned int p = ((unsigned int)m << 11) | (unsigned int)(n0 + j);
                if (pos < capacity) list[pos] = p;
                else *overflow = 1;
            }
        }
    }
}

__global__ void hg_scatter(const unsigned int* __restrict__ list,
                           const float* __restrict__ x,
                           unsigned int* __restrict__ outBits,
                           const int* __restrict__ counter,
                           int capacity) {
    const int nnz = min(*counter, capacity);
    const int total = nnz * HG_BC;
    const int stride = gridDim.x * blockDim.x;
    for (int t = blockIdx.x * blockDim.x + threadIdx.x; t < total; t += stride) {
        unsigned int p = list[t >> 5];             // 32 lanes share one entry
        int bc = t & (HG_BC - 1);
        int n = (int)(p & (HG_N_IN - 1));
        int m = (int)(p >> 11);
        float xv = x[bc * HG_N_IN + n];
        if (xv > 0.0f) {
            atomicMax(&outBits[bc * HG_N_OUT + m], __float_as_uint(xv));
        }
    }
}

// Exact dense fallback: runs per-row only when the row is all-ones (no zero to
// clamp against) or the entry list overflowed. Never triggered by this data.
__global__ void hg_fallback(const float* __restrict__ x,
                            const float* __restrict__ Bt,
                            const int* __restrict__ counts,
                            const int* __restrict__ overflow,
                            float* __restrict__ out) {
    int m = blockIdx.x * blockDim.x + threadIdx.x;
    if (m >= HG_N_OUT) return;
    bool ovf = (*overflow != 0);
    if (!ovf && counts[m] != HG_N_IN) return;
    for (int bc = 0; bc < HG_BC; ++bc) {
        float mx = -INFINITY;
        for (int n = 0; n < HG_N_IN; ++n)
            mx = fmaxf(mx, x[bc * HG_N_IN + n] * Bt[m * HG_N_IN + n]);
        out[bc * HG_N_OUT + m] = mx;
    }
}

// Pure dense path if ws is unusably small (defensive; never taken in harness).
__global__ void hg_dense(const float* __restrict__ x,
                         const float* __restrict__ Bt,
                         float* __restrict__ out) {
    int t = blockIdx.x * blockDim.x + threadIdx.x;
    if (t >= HG_BC * HG_N_OUT) return;
    int bc = t >> 12, m = t & (HG_N_OUT - 1);
    float mx = -INFINITY;
    for (int n = 0; n < HG_N_IN; ++n)
        mx = fmaxf(mx, x[bc * HG_N_IN + n] * Bt[m * HG_N_IN + n]);
    out[bc * HG_N_OUT + m] = mx;
}

extern "C" void kernel_launch(void* const* d_in, const int* in_sizes, int n_in,
                              void* d_out, int out_size, void* d_ws, size_t ws_size,
                              hipStream_t stream) {
    const float* x    = (const float*)d_in[0];     // [2,16,2048] f32
    const float* Bt   = (const float*)d_in[1];     // [4096,2048] f32
    const float4* Bt4 = (const float4*)d_in[1];
    float* out = (float*)d_out;                    // [2,16,4096] f32
    unsigned int* outBits = (unsigned int*)d_out;

    if (ws_size < WS_LIST_OFF + 4096) {            // defensive dense path
        hg_dense<<<(HG_BC * HG_N_OUT + 255) / 256, 256, 0, stream>>>(x, Bt, out);
        return;
    }

    char* ws = (char*)d_ws;
    int* counter  = (int*)(ws + 0);
    int* overflow = (int*)(ws + 4);
    int* counts   = (int*)(ws + WS_COUNTS_OFF);
    unsigned int* list = (unsigned int*)(ws + WS_LIST_OFF);
    size_t cap_sz = (ws_size - WS_LIST_OFF) / 4;
    int capacity = (cap_sz > 0x7FFFFFFF) ? 0x7FFFFFFF : (int)cap_sz;

    hipMemsetAsync(d_ws, 0, WS_LIST_OFF, stream);  // counter + flag + counts

    const int totalVec = (HG_N_OUT * HG_N_IN) / 4; // 2,097,152 float4s
    hg_compact<<<2048, 256, 0, stream>>>(Bt4, outBits, counter, overflow,
                                         counts, list, capacity, totalVec);
    hg_scatter<<<768, 256, 0, stream>>>(list, x, outBits, counter, capacity);
    hg_fallback<<<(HG_N_OUT + 255) / 256, 256, 0, stream>>>(x, Bt, counts,
                                                            overflow, out);
}

// Round 3
// 12.912 us; speedup vs baseline: 11.3417x; 11.3417x over previous
//
#include <hip/hip_runtime.h>

// out[b,c,m] = max_n x[b,c,n] * Bt[m,n],  Bt binary {0,1}, ~3 ones per row of 2048.
// Exact sparse evaluation, one block per output row m:
//   phase 1: stream Bt row m (8 KB, coalesced float4), compact nonzero column
//            indices into an LDS list (LDS atomics, ~3 per block).
//   phase 2: lanes 0..31 (one per (b,c) channel) compute
//            out[bc][m] = max(z, max_k x[bc, n_k])
//            where z = 0 if the row contains at least one zero (the dense
//            x*0 terms clamp the max at 0), else -inf (all-ones row).
// Every output element has exactly one writer -> plain stores, no atomics,
// no workspace, no memsets, single dispatch. cnt can be at most 2048, which
// the LDS list holds exactly -> no overflow path needed.

#define HG_N_IN   2048
#define HG_N_OUT  4096
#define HG_BC     32      // BATCH * FEAT = 2*16

__global__ __launch_bounds__(256) void hg_rowmax(const float4* __restrict__ Bt4,
                                                 const float* __restrict__ x,
                                                 float* __restrict__ out) {
    __shared__ unsigned short idx[HG_N_IN];
    __shared__ int lds_cnt;
    const int m = blockIdx.x;
    const int t = threadIdx.x;
    if (t == 0) lds_cnt = 0;
    __syncthreads();

    const float4* row = Bt4 + (size_t)m * (HG_N_IN / 4);
    #pragma unroll
    for (int c = 0; c < 2; ++c) {
        const int v4 = t + c * 256;              // 0..511 float4s of this row
        const float4 v = row[v4];
        const int n0 = v4 << 2;
        if (v.x != 0.0f) idx[atomicAdd(&lds_cnt, 1)] = (unsigned short)(n0);
        if (v.y != 0.0f) idx[atomicAdd(&lds_cnt, 1)] = (unsigned short)(n0 + 1);
        if (v.z != 0.0f) idx[atomicAdd(&lds_cnt, 1)] = (unsigned short)(n0 + 2);
        if (v.w != 0.0f) idx[atomicAdd(&lds_cnt, 1)] = (unsigned short)(n0 + 3);
    }
    __syncthreads();

    const int cnt = lds_cnt;
    if (t < HG_BC) {
        const float* xr = x + (size_t)t * HG_N_IN;
        float mx = (cnt == HG_N_IN) ? -INFINITY : 0.0f;  // all-ones row: no clamp
        for (int k = 0; k < cnt; ++k) {
            mx = fmaxf(mx, xr[idx[k]]);          // idx[k] broadcast across lanes
        }
        out[(size_t)t * HG_N_OUT + m] = mx;
    }
}

extern "C" void kernel_launch(void* const* d_in, const int* in_sizes, int n_in,
                              void* d_out, int out_size, void* d_ws, size_t ws_size,
                              hipStream_t stream) {
    const float* x    = (const float*)d_in[0];   // [2,16,2048] f32
    const float4* Bt4 = (const float4*)d_in[1];  // [4096,2048] f32 as float4
    float* out = (float*)d_out;                  // [2,16,4096] f32

    hg_rowmax<<<HG_N_OUT, 256, 0, stream>>>(Bt4, x, out);
}